// Round 2
// baseline (1031.010 us; speedup 1.0000x reference)
//
#include <hip/hip_runtime.h>

// SAGPool: h0/h1 scalar projections -> edge scatter-add -> tanh -> segment max.
// V = 2e6, C = 128, E = 6e6, B = 64.
// NOTE: harness delivers ALL integer inputs as int32 (int64 in reference
// is converted). edges = int32[E][2], verts_idx = int32[V].

constexpr int C = 128;

// ---- monotonic float <-> uint encoding for atomicMax on floats ----
__device__ __forceinline__ unsigned int enc_f32(float f) {
    unsigned int b = __float_as_uint(f);
    return (b & 0x80000000u) ? ~b : (b | 0x80000000u);
}
__device__ __forceinline__ float dec_f32(unsigned int u) {
    unsigned int b = (u & 0x80000000u) ? (u ^ 0x80000000u) : ~u;
    return __uint_as_float(b);
}

// init the B per-mesh maxima to encoding of -inf
__global__ void k_init(unsigned int* __restrict__ umax, int B) {
    int i = blockIdx.x * blockDim.x + threadIdx.x;
    if (i < B) umax[i] = enc_f32(-__builtin_huge_valf());
}

// diagnostic path if workspace too small: emit ws_size so absmax reveals it
__global__ void k_diag(float* __restrict__ out, int B, float v) {
    int i = blockIdx.x * blockDim.x + threadIdx.x;
    if (i < B) out[i] = v;
}

// 32 lanes per vertex; lane reads one float4 (16B) -> coalesced 512B/row.
// acc[v] = h0[v] (nbr accumulator seeded with h0), h1out[v] = h1[v].
__global__ void k_vertex(const float* __restrict__ verts,
                         const float* __restrict__ w0, const float* __restrict__ b0,
                         const float* __restrict__ w1, const float* __restrict__ b1,
                         float* __restrict__ acc, float* __restrict__ h1out,
                         int V) {
    int tid = blockIdx.x * blockDim.x + threadIdx.x;
    int sub = tid & 31;       // lane within 32-group
    int v   = tid >> 5;       // vertex
    if (v >= V) return;       // uniform across each 32-group

    float4 wv0 = *reinterpret_cast<const float4*>(w0 + sub * 4);
    float4 wv1 = *reinterpret_cast<const float4*>(w1 + sub * 4);
    float4 x   = *reinterpret_cast<const float4*>(verts + (size_t)v * C + sub * 4);

    float d0 = x.x * wv0.x + x.y * wv0.y + x.z * wv0.z + x.w * wv0.w;
    float d1 = x.x * wv1.x + x.y * wv1.y + x.z * wv1.z + x.w * wv1.w;

    #pragma unroll
    for (int off = 16; off >= 1; off >>= 1) {
        d0 += __shfl_xor(d0, off, 32);
        d1 += __shfl_xor(d1, off, 32);
    }
    if (sub == 0) {
        acc[v]   = d0 + b0[0];
        h1out[v] = d1 + b1[0];
    }
}

// one edge per thread; coalesced 8B int2 edge load; two scatter atomics.
__global__ void k_edge(const int* __restrict__ edges,
                       const float* __restrict__ h1,
                       float* __restrict__ acc, int E) {
    int e = blockIdx.x * blockDim.x + threadIdx.x;
    if (e >= E) return;
    int2 p = reinterpret_cast<const int2*>(edges)[e];
    int s = p.x, d = p.y;
    float hs = h1[s], hd = h1[d];
    atomicAdd(&acc[s], hd);
    atomicAdd(&acc[d], hs);
}

// tanh + segment max. verts_idx sorted -> waves almost always mesh-uniform:
// wave-reduce max, one atomic per wave. Boundary/tail waves fall back per-lane.
__global__ void k_pool(const float* __restrict__ acc,
                       const int* __restrict__ vidx,
                       unsigned int* __restrict__ umax, int V) {
    int v = blockIdx.x * blockDim.x + threadIdx.x;
    bool valid = v < V;
    int m = -1;
    unsigned int u = 0u;  // below every real encoding; neutral for max
    if (valid) {
        float s = tanhf(acc[v]);
        m = vidx[v];
        u = enc_f32(s);
    }
    int m0 = __shfl(m, 0);
    if (__all(m == m0)) {
        if (m0 >= 0) {
            #pragma unroll
            for (int off = 32; off >= 1; off >>= 1) {
                unsigned int o = __shfl_xor(u, off);
                u = (o > u) ? o : u;
            }
            if ((threadIdx.x & 63) == 0) atomicMax(&umax[m0], u);
        }
    } else {
        if (valid) atomicMax(&umax[m], u);
    }
}

__global__ void k_decode(const unsigned int* __restrict__ umax,
                         float* __restrict__ out, int B) {
    int i = blockIdx.x * blockDim.x + threadIdx.x;
    if (i < B) out[i] = dec_f32(umax[i]);
}

extern "C" void kernel_launch(void* const* d_in, const int* in_sizes, int n_in,
                              void* d_out, int out_size, void* d_ws, size_t ws_size,
                              hipStream_t stream) {
    const float* verts = (const float*)d_in[0];
    const int*   edges = (const int*)d_in[1];   // int32 on device
    const int*   vidx  = (const int*)d_in[2];   // int32 on device
    // d_in[3] = edges_idx (unused), d_in[4] = num_meshes scalar (unused)
    const float* w0 = (const float*)d_in[5];
    const float* b0 = (const float*)d_in[6];
    const float* w1 = (const float*)d_in[7];
    const float* b1 = (const float*)d_in[8];
    float* out = (float*)d_out;

    const int V = in_sizes[0] / C;
    const int E = in_sizes[1] / 2;
    const int B = out_size;

    const size_t need = (size_t)V * 4 * 2 + (size_t)B * 4;
    if (ws_size < need) {
        // diagnostic: absmax will show ~ws_size instead of a memory fault
        hipLaunchKernelGGL(k_diag, dim3(1), dim3(256), 0, stream,
                           out, B, (float)ws_size);
        return;
    }

    float* acc = (float*)d_ws;                       // V floats
    float* h1  = acc + V;                            // V floats
    unsigned int* umax = (unsigned int*)(h1 + V);    // B uints

    hipLaunchKernelGGL(k_init, dim3(1), dim3(256), 0, stream, umax, B);

    {
        long long threads = (long long)V * 32;
        int block = 256;
        unsigned grid = (unsigned)((threads + block - 1) / block);
        hipLaunchKernelGGL(k_vertex, dim3(grid), dim3(block), 0, stream,
                           verts, w0, b0, w1, b1, acc, h1, V);
    }

    hipLaunchKernelGGL(k_edge, dim3((E + 255) / 256), dim3(256), 0, stream,
                       edges, h1, acc, E);

    hipLaunchKernelGGL(k_pool, dim3((V + 255) / 256), dim3(256), 0, stream,
                       acc, vidx, umax, V);

    hipLaunchKernelGGL(k_decode, dim3(1), dim3(256), 0, stream, umax, out, B);
}

// Round 4
// 838.507 us; speedup vs baseline: 1.2296x; 1.2296x over previous
//
#include <hip/hip_runtime.h>

// SAGPool: h0/h1 scalar projections -> edge scatter-add -> tanh -> segment max.
// V = 2e6, C = 128, E = 6e6, B = 64. All int inputs arrive as int32.

constexpr int C = 128;

typedef float vfloat4 __attribute__((ext_vector_type(4)));

__device__ __forceinline__ unsigned int enc_f32(float f) {
    unsigned int b = __float_as_uint(f);
    return (b & 0x80000000u) ? ~b : (b | 0x80000000u);
}
__device__ __forceinline__ float dec_f32(unsigned int u) {
    unsigned int b = (u & 0x80000000u) ? (u ^ 0x80000000u) : ~u;
    return __uint_as_float(b);
}

__global__ void k_init(unsigned int* __restrict__ umax, int B) {
    int i = blockIdx.x * blockDim.x + threadIdx.x;
    if (i < B) umax[i] = enc_f32(-__builtin_huge_valf());
}

__global__ void k_diag(float* __restrict__ out, int B, float v) {
    int i = blockIdx.x * blockDim.x + threadIdx.x;
    if (i < B) out[i] = v;
}

// 16 lanes per vertex; each lane reads 2x float4 (32B) -> coalesced.
// acc[v] = h0[v] (nbr accumulator seeded with h0), h1out[v] = h1[v].
__global__ __launch_bounds__(256) void k_vertex(
        const float* __restrict__ verts,
        const float* __restrict__ w0, const float* __restrict__ b0,
        const float* __restrict__ w1, const float* __restrict__ b1,
        float* __restrict__ acc, float* __restrict__ h1out,
        int V) {
    int tid = blockIdx.x * blockDim.x + threadIdx.x;
    int sub = tid & 15;       // lane within 16-group
    int v   = tid >> 4;       // vertex
    if (v >= V) return;       // uniform across each 16-group

    const vfloat4* row = reinterpret_cast<const vfloat4*>(verts + (size_t)v * C);
    const vfloat4* W0  = reinterpret_cast<const vfloat4*>(w0);
    const vfloat4* W1  = reinterpret_cast<const vfloat4*>(w1);

    vfloat4 x0 = __builtin_nontemporal_load(&row[sub]);
    vfloat4 x1 = __builtin_nontemporal_load(&row[sub + 16]);
    vfloat4 a0 = W0[sub], a1 = W0[sub + 16];
    vfloat4 c0 = W1[sub], c1 = W1[sub + 16];

    float d0 = x0.x * a0.x + x0.y * a0.y + x0.z * a0.z + x0.w * a0.w
             + x1.x * a1.x + x1.y * a1.y + x1.z * a1.z + x1.w * a1.w;
    float d1 = x0.x * c0.x + x0.y * c0.y + x0.z * c0.z + x0.w * c0.w
             + x1.x * c1.x + x1.y * c1.y + x1.z * c1.z + x1.w * c1.w;

    #pragma unroll
    for (int off = 8; off >= 1; off >>= 1) {
        d0 += __shfl_xor(d0, off);
        d1 += __shfl_xor(d1, off);
    }
    if (sub == 0) {
        acc[v]   = d0 + b0[0];
        h1out[v] = d1 + b1[0];
    }
}

// two edges per thread via one int4 load; four gathers, four atomics.
__global__ __launch_bounds__(256) void k_edge(
        const int* __restrict__ edges,
        const float* __restrict__ h1,
        float* __restrict__ acc, int E) {
    int t = blockIdx.x * blockDim.x + threadIdx.x;
    int E2 = E >> 1;
    if (t < E2) {
        int4 p = reinterpret_cast<const int4*>(edges)[t];
        float ha = h1[p.x], hb = h1[p.y], hc = h1[p.z], hd = h1[p.w];
        atomicAdd(&acc[p.x], hb);
        atomicAdd(&acc[p.y], ha);
        atomicAdd(&acc[p.z], hd);
        atomicAdd(&acc[p.w], hc);
    } else if (t == E2 && (E & 1)) {  // odd tail edge
        int s = edges[(size_t)(E - 1) * 2], d = edges[(size_t)(E - 1) * 2 + 1];
        float hs = h1[s], hd = h1[d];
        atomicAdd(&acc[s], hd);
        atomicAdd(&acc[d], hs);
    }
}

// tanh + segment max, 4 vertices/thread. verts_idx sorted -> fast wave path.
__global__ __launch_bounds__(256) void k_pool(
        const float* __restrict__ acc,
        const int* __restrict__ vidx,
        unsigned int* __restrict__ umax, int V) {
    int t = blockIdx.x * blockDim.x + threadIdx.x;
    int V4 = V >> 2;
    bool valid = t < V4;

    int mlo = -1, mhi = -1;
    unsigned int u0 = 0, u1 = 0, u2 = 0, u3 = 0;
    if (valid) {
        float4 a = reinterpret_cast<const float4*>(acc)[t];
        int4   m = reinterpret_cast<const int4*>(vidx)[t];
        u0 = enc_f32(tanhf(a.x)); u1 = enc_f32(tanhf(a.y));
        u2 = enc_f32(tanhf(a.z)); u3 = enc_f32(tanhf(a.w));
        mlo = m.x; mhi = m.w;     // sorted: uniform iff mlo==mhi
    }
    unsigned int um = max(max(u0, u1), max(u2, u3));

    int wlo = __shfl(mlo, 0);
    int whi = __shfl(mhi, 63);
    if (wlo == whi && __all(valid) && wlo >= 0) {
        #pragma unroll
        for (int off = 32; off >= 1; off >>= 1) {
            unsigned int o = __shfl_xor(um, off);
            um = (o > um) ? o : um;
        }
        if ((threadIdx.x & 63) == 0) atomicMax(&umax[wlo], um);
    } else if (valid) {
        if (mlo == mhi) {
            atomicMax(&umax[mlo], um);
        } else {
            int4 m = reinterpret_cast<const int4*>(vidx)[t];
            atomicMax(&umax[m.x], u0);
            atomicMax(&umax[m.y], u1);
            atomicMax(&umax[m.z], u2);
            atomicMax(&umax[m.w], u3);
        }
    }
    // scalar tail (V not divisible by 4): first few threads cover it
    int rem = V & 3;
    if (t < rem) {
        int v = V4 * 4 + t;
        atomicMax(&umax[vidx[v]], enc_f32(tanhf(acc[v])));
    }
}

__global__ void k_decode(const unsigned int* __restrict__ umax,
                         float* __restrict__ out, int B) {
    int i = blockIdx.x * blockDim.x + threadIdx.x;
    if (i < B) out[i] = dec_f32(umax[i]);
}

extern "C" void kernel_launch(void* const* d_in, const int* in_sizes, int n_in,
                              void* d_out, int out_size, void* d_ws, size_t ws_size,
                              hipStream_t stream) {
    const float* verts = (const float*)d_in[0];
    const int*   edges = (const int*)d_in[1];   // int32 on device
    const int*   vidx  = (const int*)d_in[2];   // int32 on device
    const float* w0 = (const float*)d_in[5];
    const float* b0 = (const float*)d_in[6];
    const float* w1 = (const float*)d_in[7];
    const float* b1 = (const float*)d_in[8];
    float* out = (float*)d_out;

    const int V = in_sizes[0] / C;
    const int E = in_sizes[1] / 2;
    const int B = out_size;

    const size_t need = (size_t)V * 4 * 2 + (size_t)B * 4;
    if (ws_size < need) {
        hipLaunchKernelGGL(k_diag, dim3(1), dim3(256), 0, stream,
                           out, B, (float)ws_size);
        return;
    }

    float* acc = (float*)d_ws;                       // V floats
    float* h1  = acc + V;                            // V floats
    unsigned int* umax = (unsigned int*)(h1 + V);    // B uints

    hipLaunchKernelGGL(k_init, dim3(1), dim3(64), 0, stream, umax, B);

    {
        long long threads = (long long)V * 16;
        unsigned grid = (unsigned)((threads + 255) / 256);
        hipLaunchKernelGGL(k_vertex, dim3(grid), dim3(256), 0, stream,
                           verts, w0, b0, w1, b1, acc, h1, V);
    }

    {
        int work = (E >> 1) + 1;  // pair-threads + tail slot
        hipLaunchKernelGGL(k_edge, dim3((work + 255) / 256), dim3(256), 0, stream,
                           edges, h1, acc, E);
    }

    {
        int work = (V >> 2) + 4;
        hipLaunchKernelGGL(k_pool, dim3((work + 255) / 256), dim3(256), 0, stream,
                           acc, vidx, umax, V);
    }

    hipLaunchKernelGGL(k_decode, dim3(1), dim3(64), 0, stream, umax, out, B);
}

// Round 5
// 829.122 us; speedup vs baseline: 1.2435x; 1.0113x over previous
//
#include <hip/hip_runtime.h>

// SAGPool: h0/h1 scalar projections -> edge scatter-add -> tanh -> segment max.
// V = 2e6, C = 128, E = 6e6, B = 64. All int inputs arrive as int32.

constexpr int C = 128;

typedef float vfloat4 __attribute__((ext_vector_type(4)));
typedef int   vint4   __attribute__((ext_vector_type(4)));

__device__ __forceinline__ unsigned int enc_f32(float f) {
    unsigned int b = __float_as_uint(f);
    return (b & 0x80000000u) ? ~b : (b | 0x80000000u);
}
__device__ __forceinline__ float dec_f32(unsigned int u) {
    unsigned int b = (u & 0x80000000u) ? (u ^ 0x80000000u) : ~u;
    return __uint_as_float(b);
}

__global__ void k_diag(float* __restrict__ out, int B, float v) {
    int i = blockIdx.x * blockDim.x + threadIdx.x;
    if (i < B) out[i] = v;
}

// 8 lanes per vertex; each lane reads 4x float4 (64B) -> coalesced.
// acc[v] = h0[v] (nbr accumulator seeded with h0), h1out[v] = h1[v].
// Block 0 also initializes umax (saves a separate launch).
__global__ __launch_bounds__(256) void k_vertex(
        const float* __restrict__ verts,
        const float* __restrict__ w0, const float* __restrict__ b0,
        const float* __restrict__ w1, const float* __restrict__ b1,
        float* __restrict__ acc, float* __restrict__ h1out,
        unsigned int* __restrict__ umax, int V, int B) {
    if (blockIdx.x == 0 && threadIdx.x < (unsigned)B)
        umax[threadIdx.x] = enc_f32(-__builtin_huge_valf());

    int tid = blockIdx.x * blockDim.x + threadIdx.x;
    int sub = tid & 7;        // lane within 8-group
    int v   = tid >> 3;       // vertex
    if (v >= V) return;       // uniform across each 8-group

    const vfloat4* row = reinterpret_cast<const vfloat4*>(verts + (size_t)v * C);
    const vfloat4* W0  = reinterpret_cast<const vfloat4*>(w0);
    const vfloat4* W1  = reinterpret_cast<const vfloat4*>(w1);

    vfloat4 x0 = __builtin_nontemporal_load(&row[sub]);
    vfloat4 x1 = __builtin_nontemporal_load(&row[sub + 8]);
    vfloat4 x2 = __builtin_nontemporal_load(&row[sub + 16]);
    vfloat4 x3 = __builtin_nontemporal_load(&row[sub + 24]);

    vfloat4 a0 = W0[sub], a1 = W0[sub + 8], a2 = W0[sub + 16], a3 = W0[sub + 24];
    vfloat4 c0 = W1[sub], c1 = W1[sub + 8], c2 = W1[sub + 16], c3 = W1[sub + 24];

    float d0 = x0.x*a0.x + x0.y*a0.y + x0.z*a0.z + x0.w*a0.w
             + x1.x*a1.x + x1.y*a1.y + x1.z*a1.z + x1.w*a1.w
             + x2.x*a2.x + x2.y*a2.y + x2.z*a2.z + x2.w*a2.w
             + x3.x*a3.x + x3.y*a3.y + x3.z*a3.z + x3.w*a3.w;
    float d1 = x0.x*c0.x + x0.y*c0.y + x0.z*c0.z + x0.w*c0.w
             + x1.x*c1.x + x1.y*c1.y + x1.z*c1.z + x1.w*c1.w
             + x2.x*c2.x + x2.y*c2.y + x2.z*c2.z + x2.w*c2.w
             + x3.x*c3.x + x3.y*c3.y + x3.z*c3.z + x3.w*c3.w;

    #pragma unroll
    for (int off = 4; off >= 1; off >>= 1) {
        d0 += __shfl_xor(d0, off);
        d1 += __shfl_xor(d1, off);
    }
    if (sub == 0) {
        acc[v]   = d0 + b0[0];
        h1out[v] = d1 + b1[0];
    }
}

// four edges per thread via two nt int4 loads; 8 gathers, 8 atomics.
__global__ __launch_bounds__(256) void k_edge(
        const int* __restrict__ edges,
        const float* __restrict__ h1,
        float* __restrict__ acc, int E) {
    int t = blockIdx.x * blockDim.x + threadIdx.x;
    int E4 = E >> 2;
    const vint4* e4 = reinterpret_cast<const vint4*>(edges);
    if (t < E4) {
        vint4 p = __builtin_nontemporal_load(&e4[2 * t]);
        vint4 q = __builtin_nontemporal_load(&e4[2 * t + 1]);
        float hpx = h1[p.x], hpy = h1[p.y], hpz = h1[p.z], hpw = h1[p.w];
        float hqx = h1[q.x], hqy = h1[q.y], hqz = h1[q.z], hqw = h1[q.w];
        atomicAdd(&acc[p.x], hpy);
        atomicAdd(&acc[p.y], hpx);
        atomicAdd(&acc[p.z], hpw);
        atomicAdd(&acc[p.w], hpz);
        atomicAdd(&acc[q.x], hqy);
        atomicAdd(&acc[q.y], hqx);
        atomicAdd(&acc[q.z], hqw);
        atomicAdd(&acc[q.w], hqz);
    } else if (t == E4) {
        for (int e = E4 * 4; e < E; ++e) {   // tail (E % 4 edges)
            int s = edges[(size_t)e * 2], d = edges[(size_t)e * 2 + 1];
            float hs = h1[s], hd = h1[d];
            atomicAdd(&acc[s], hd);
            atomicAdd(&acc[d], hs);
        }
    }
}

// tanh + segment max, 4 vertices/thread. verts_idx sorted -> fast wave path.
__global__ __launch_bounds__(256) void k_pool(
        const float* __restrict__ acc,
        const int* __restrict__ vidx,
        unsigned int* __restrict__ umax, int V) {
    int t = blockIdx.x * blockDim.x + threadIdx.x;
    int V4 = V >> 2;
    bool valid = t < V4;

    int mlo = -1, mhi = -1;
    unsigned int u0 = 0, u1 = 0, u2 = 0, u3 = 0;
    if (valid) {
        float4 a = reinterpret_cast<const float4*>(acc)[t];
        int4   m = reinterpret_cast<const int4*>(vidx)[t];
        u0 = enc_f32(tanhf(a.x)); u1 = enc_f32(tanhf(a.y));
        u2 = enc_f32(tanhf(a.z)); u3 = enc_f32(tanhf(a.w));
        mlo = m.x; mhi = m.w;     // sorted: uniform iff mlo==mhi
    }
    unsigned int um = max(max(u0, u1), max(u2, u3));

    int wlo = __shfl(mlo, 0);
    int whi = __shfl(mhi, 63);
    if (wlo == whi && __all(valid) && wlo >= 0) {
        #pragma unroll
        for (int off = 32; off >= 1; off >>= 1) {
            unsigned int o = __shfl_xor(um, off);
            um = (o > um) ? o : um;
        }
        if ((threadIdx.x & 63) == 0) atomicMax(&umax[wlo], um);
    } else if (valid) {
        if (mlo == mhi) {
            atomicMax(&umax[mlo], um);
        } else {
            int4 m = reinterpret_cast<const int4*>(vidx)[t];
            atomicMax(&umax[m.x], u0);
            atomicMax(&umax[m.y], u1);
            atomicMax(&umax[m.z], u2);
            atomicMax(&umax[m.w], u3);
        }
    }
    // scalar tail (V not divisible by 4)
    int rem = V & 3;
    if (t < rem) {
        int v = V4 * 4 + t;
        atomicMax(&umax[vidx[v]], enc_f32(tanhf(acc[v])));
    }
}

__global__ void k_decode(const unsigned int* __restrict__ umax,
                         float* __restrict__ out, int B) {
    int i = blockIdx.x * blockDim.x + threadIdx.x;
    if (i < B) out[i] = dec_f32(umax[i]);
}

extern "C" void kernel_launch(void* const* d_in, const int* in_sizes, int n_in,
                              void* d_out, int out_size, void* d_ws, size_t ws_size,
                              hipStream_t stream) {
    const float* verts = (const float*)d_in[0];
    const int*   edges = (const int*)d_in[1];   // int32 on device
    const int*   vidx  = (const int*)d_in[2];   // int32 on device
    const float* w0 = (const float*)d_in[5];
    const float* b0 = (const float*)d_in[6];
    const float* w1 = (const float*)d_in[7];
    const float* b1 = (const float*)d_in[8];
    float* out = (float*)d_out;

    const int V = in_sizes[0] / C;
    const int E = in_sizes[1] / 2;
    const int B = out_size;

    const size_t need = (size_t)V * 4 * 2 + (size_t)B * 4;
    if (ws_size < need) {
        hipLaunchKernelGGL(k_diag, dim3(1), dim3(256), 0, stream,
                           out, B, (float)ws_size);
        return;
    }

    float* acc = (float*)d_ws;                       // V floats
    float* h1  = acc + V;                            // V floats
    unsigned int* umax = (unsigned int*)(h1 + V);    // B uints

    {
        long long threads = (long long)V * 8;
        unsigned grid = (unsigned)((threads + 255) / 256);
        hipLaunchKernelGGL(k_vertex, dim3(grid), dim3(256), 0, stream,
                           verts, w0, b0, w1, b1, acc, h1, umax, V, B);
    }

    {
        int work = (E >> 2) + 1;  // quad-threads + tail slot
        hipLaunchKernelGGL(k_edge, dim3((work + 255) / 256), dim3(256), 0, stream,
                           edges, h1, acc, E);
    }

    {
        int work = (V >> 2) + 4;
        hipLaunchKernelGGL(k_pool, dim3((work + 255) / 256), dim3(256), 0, stream,
                           acc, vidx, umax, V);
    }

    hipLaunchKernelGGL(k_decode, dim3(1), dim3(64), 0, stream, umax, out, B);
}